// Round 1
// baseline (913.104 us; speedup 1.0000x reference)
//
#include <hip/hip_runtime.h>

#define Bdim 64
#define Ndim 512
#define Hdim 2048
#define KSPLIT 8
#define KRANGE (Hdim / KSPLIT)   // 256
#define KCHUNK 64
#define OCHUNK 32
#define NCHUNK 8
#define LNEPS 1e-5f

__device__ __forceinline__ unsigned short f2bf(float f) {
    unsigned int u = __float_as_uint(f);
    return (unsigned short)((u + 0x7FFFu + ((u >> 16) & 1u)) >> 16);
}
__device__ __forceinline__ float bf2f(unsigned short s) {
    return __uint_as_float(((unsigned int)s) << 16);
}

// Partial GEMV: part[ks][b][o] = sum_{k in ks-range} X[b,k] * Weff[o,k]
// WMODE 0: Weff[o,k] = W[o*H + k]   (Y = X @ W^T)
// WMODE 1: Weff[o,k] = W[k*H + o]   (Y = X @ W)
template<int WMODE>
__global__ __launch_bounds__(256)
void gemv_main(const float* __restrict__ X, const float* __restrict__ W,
               float* __restrict__ part)
{
    __shared__ float Xs[64][68];
    __shared__ float Ws[OCHUNK][68];
    const int t  = threadIdx.x;
    const int oc = blockIdx.x & 63;   // 64 o-chunks of 32
    const int ks = blockIdx.x >> 6;   // 8 k-splits
    const int o0 = oc * OCHUNK;
    const int kb = ks * KRANGE;
    const int og = t & 7;             // o-group of 4
    const int bg = t >> 3;            // 0..31 -> b pair
    float acc[2][4];
#pragma unroll
    for (int j = 0; j < 2; ++j)
#pragma unroll
        for (int oi = 0; oi < 4; ++oi) acc[j][oi] = 0.f;

    for (int kc = 0; kc < KRANGE; kc += KCHUNK) {
        const int k0 = kb + kc;
        // stage X[64][64]
#pragma unroll
        for (int i = 0; i < 4; ++i) {
            int flat = i * 256 + t;
            int row  = flat >> 4;
            int c4   = flat & 15;
            float4 v = *(const float4*)(X + (size_t)row * Hdim + k0 + c4 * 4);
            *(float4*)(&Xs[row][c4 * 4]) = v;
        }
        // stage W tile as Ws[o_local][k_local]
        if (WMODE == 0) {
#pragma unroll
            for (int i = 0; i < 2; ++i) {
                int flat = i * 256 + t;
                int row  = flat >> 4;   // o_local 0..31
                int c4   = flat & 15;
                float4 v = *(const float4*)(W + (size_t)(o0 + row) * Hdim + k0 + c4 * 4);
                *(float4*)(&Ws[row][c4 * 4]) = v;
            }
        } else {
#pragma unroll
            for (int i = 0; i < 2; ++i) {
                int flat = i * 256 + t;
                int row  = flat >> 3;   // k_local 0..63
                int c4   = flat & 7;    // o quad
                float4 v = *(const float4*)(W + (size_t)(k0 + row) * Hdim + o0 + c4 * 4);
                Ws[c4 * 4 + 0][row] = v.x;
                Ws[c4 * 4 + 1][row] = v.y;
                Ws[c4 * 4 + 2][row] = v.z;
                Ws[c4 * 4 + 3][row] = v.w;
            }
        }
        __syncthreads();
#pragma unroll
        for (int kk = 0; kk < KCHUNK; kk += 4) {
            float4 x0 = *(const float4*)(&Xs[bg * 2 + 0][kk]);
            float4 x1 = *(const float4*)(&Xs[bg * 2 + 1][kk]);
#pragma unroll
            for (int oi = 0; oi < 4; ++oi) {
                float4 w = *(const float4*)(&Ws[og * 4 + oi][kk]);
                acc[0][oi] += x0.x * w.x + x0.y * w.y + x0.z * w.z + x0.w * w.w;
                acc[1][oi] += x1.x * w.x + x1.y * w.y + x1.z * w.z + x1.w * w.w;
            }
        }
        __syncthreads();
    }
#pragma unroll
    for (int j = 0; j < 2; ++j) {
        int b = bg * 2 + j;
#pragma unroll
        for (int oi = 0; oi < 4; ++oi) {
            part[(size_t)(ks * 64 + b) * Hdim + o0 + og * 4 + oi] = acc[j][oi];
        }
    }
}

// Y[b,o] (=|+=) sum_s part[s][b][o] (+ bias[o])
template<int ACC, int HASBIAS>
__global__ __launch_bounds__(256)
void combine(const float* __restrict__ part, const float* __restrict__ bias,
             float* __restrict__ Y)
{
    const int flat4 = blockIdx.x * 256 + threadIdx.x;   // 0..32767
    const size_t e  = (size_t)flat4 * 4;
    const int o     = (int)(e & (Hdim - 1));
    float4 v;
    if (HASBIAS) v = *(const float4*)(bias + o);
    else { v.x = 0.f; v.y = 0.f; v.z = 0.f; v.w = 0.f; }
#pragma unroll
    for (int s = 0; s < KSPLIT; ++s) {
        float4 p = *(const float4*)(part + (size_t)s * (64 * Hdim) + e);
        v.x += p.x; v.y += p.y; v.z += p.z; v.w += p.w;
    }
    if (ACC) {
        float4 a = *(const float4*)(Y + e);
        v.x += a.x; v.y += a.y; v.z += a.z; v.w += a.w;
    }
    *(float4*)(Y + e) = v;
}

// One (b, 8-row n-chunk): scores -> local softmax -> partial weighted lfb sum.
__global__ __launch_bounds__(256)
void flash_chunk(const float* __restrict__ lfb, const float* __restrict__ thetal,
                 float scale, float* __restrict__ up,
                 float* __restrict__ wm, float* __restrict__ wz)
{
    __shared__ unsigned short T[NCHUNK][Hdim];   // bf16 tile, 32 KB
    __shared__ float th[Hdim];                   // 8 KB
    __shared__ float sc[NCHUNK];
    __shared__ float wts[NCHUNK];
    const int t  = threadIdx.x;
    const int b  = blockIdx.x >> 6;
    const int ch = blockIdx.x & 63;
    const float* src = lfb + ((size_t)b * Ndim + ch * NCHUNK) * Hdim;
#pragma unroll
    for (int i = 0; i < 16; ++i) {
        int flat4 = i * 256 + t;        // 0..4095
        int row   = flat4 >> 9;
        int c4    = flat4 & 511;
        float4 v  = *(const float4*)(src + (size_t)row * Hdim + c4 * 4);
        ushort4 u4;
        u4.x = f2bf(v.x); u4.y = f2bf(v.y); u4.z = f2bf(v.z); u4.w = f2bf(v.w);
        *(ushort4*)(&T[row][c4 * 4]) = u4;
    }
#pragma unroll
    for (int i = 0; i < 2; ++i) {
        int c = (i * 256 + t) * 4;
        float4 v = *(const float4*)(thetal + (size_t)b * Hdim + c);
        *(float4*)(&th[c]) = v;
    }
    __syncthreads();
    const int wv = t >> 6, ln = t & 63;
#pragma unroll
    for (int q = 0; q < 2; ++q) {
        int n = wv * 2 + q;
        float a = 0.f;
#pragma unroll
        for (int i = 0; i < 8; ++i) {
            int c = ln * 4 + i * 256;
            ushort4 x = *(const ushort4*)(&T[n][c]);
            float4 y  = *(const float4*)(&th[c]);
            a += bf2f(x.x) * y.x + bf2f(x.y) * y.y + bf2f(x.z) * y.z + bf2f(x.w) * y.w;
        }
#pragma unroll
        for (int off = 32; off; off >>= 1) a += __shfl_xor(a, off, 64);
        if (ln == 0) sc[n] = a * scale;
    }
    __syncthreads();
    float m = sc[0];
#pragma unroll
    for (int n = 1; n < NCHUNK; ++n) m = fmaxf(m, sc[n]);
    if (t < NCHUNK) wts[t] = expf(sc[t] - m);
    __syncthreads();
    if (t == 0) {
        float z = 0.f;
#pragma unroll
        for (int n = 0; n < NCHUNK; ++n) z += wts[n];
        wm[blockIdx.x] = m;
        wz[blockIdx.x] = z;
    }
#pragma unroll
    for (int i = 0; i < 8; ++i) {
        int c = t + i * 256;
        float a = 0.f;
#pragma unroll
        for (int n = 0; n < NCHUNK; ++n) a += wts[n] * bf2f(T[n][c]);
        up[(size_t)blockIdx.x * Hdim + c] = a;
    }
}

__global__ __launch_bounds__(256)
void flash_combine(const float* __restrict__ up, const float* __restrict__ wm,
                   const float* __restrict__ wz, float* __restrict__ u)
{
    __shared__ float mm[64], zz[64], ee[64];
    const int t = threadIdx.x, b = blockIdx.x;
    if (t < 64) { mm[t] = wm[b * 64 + t]; zz[t] = wz[b * 64 + t]; }
    __syncthreads();
    float mg = mm[0];
#pragma unroll
    for (int i = 1; i < 64; ++i) mg = fmaxf(mg, mm[i]);
    if (t < 64) ee[t] = expf(mm[t] - mg);
    __syncthreads();
    float Zg = 0.f;
#pragma unroll
    for (int i = 0; i < 64; ++i) Zg += zz[i] * ee[i];
    const float inv = 1.f / Zg;
#pragma unroll
    for (int i = 0; i < 8; ++i) {
        int c = t + i * 256;
        float a = 0.f;
        for (int ch = 0; ch < 64; ++ch)
            a += up[((size_t)b * 64 + ch) * Hdim + c] * ee[ch];
        u[(size_t)b * Hdim + c] = a * inv;
    }
}

// r = relu(layernorm(sum_s part[s][b][:] + bias))
__global__ __launch_bounds__(256)
void ln_relu_from_part(const float* __restrict__ part, const float* __restrict__ bias,
                       float* __restrict__ r)
{
    __shared__ float trow[Hdim];
    __shared__ float red[8];
    const int t = threadIdx.x, b = blockIdx.x;
    float sum = 0.f, sq = 0.f;
#pragma unroll
    for (int i = 0; i < 2; ++i) {
        int c = (i * 256 + t) * 4;
        float4 v = *(const float4*)(bias + c);
#pragma unroll
        for (int s = 0; s < KSPLIT; ++s) {
            float4 p = *(const float4*)(part + ((size_t)(s * 64 + b)) * Hdim + c);
            v.x += p.x; v.y += p.y; v.z += p.z; v.w += p.w;
        }
        *(float4*)(&trow[c]) = v;
        sum += v.x + v.y + v.z + v.w;
        sq  += v.x * v.x + v.y * v.y + v.z * v.z + v.w * v.w;
    }
#pragma unroll
    for (int off = 32; off; off >>= 1) {
        sum += __shfl_xor(sum, off, 64);
        sq  += __shfl_xor(sq,  off, 64);
    }
    if ((t & 63) == 0) { red[t >> 6] = sum; red[4 + (t >> 6)] = sq; }
    __syncthreads();
    sum = red[0] + red[1] + red[2] + red[3];
    sq  = red[4] + red[5] + red[6] + red[7];
    const float mu   = sum * (1.f / Hdim);
    const float var  = sq * (1.f / Hdim) - mu * mu;
    const float rstd = rsqrtf(var + LNEPS);
#pragma unroll
    for (int i = 0; i < 2; ++i) {
        int c = (i * 256 + t) * 4;
        float4 v = *(const float4*)(&trow[c]);
        float4 o;
        o.x = fmaxf(0.f, (v.x - mu) * rstd);
        o.y = fmaxf(0.f, (v.y - mu) * rstd);
        o.z = fmaxf(0.f, (v.z - mu) * rstd);
        o.w = fmaxf(0.f, (v.w - mu) * rstd);
        *(float4*)(r + (size_t)b * Hdim + c) = o;
    }
}

__global__ __launch_bounds__(256)
void finalize_k(const float* __restrict__ A, float* __restrict__ out, int has_loss)
{
    const int flat4 = blockIdx.x * 256 + threadIdx.x;
    float4 v = *(const float4*)(A + (size_t)flat4 * 4);
    *(float4*)(out + (size_t)flat4 * 4) = v;
    if (has_loss && flat4 == 0) out[Bdim * Hdim] = 0.f;
}

extern "C" void kernel_launch(void* const* d_in, const int* in_sizes, int n_in,
                              void* d_out, int out_size, void* d_ws, size_t ws_size,
                              hipStream_t stream) {
    (void)in_sizes; (void)n_in; (void)ws_size;
    const float* clip = (const float*)d_in[0];
    const float* lfb  = (const float*)d_in[1];
    const float* Wc   = (const float*)d_in[2];
    const float* bc   = (const float*)d_in[3];
    const float* Wl   = (const float*)d_in[4];
    const float* bl   = (const float*)d_in[5];
    const float* Wt   = (const float*)d_in[6];
    const float* bt   = (const float*)d_in[7];
    const float* Wp   = (const float*)d_in[8];
    // d_in[9] = bp: cancels inside softmax (constant shift per row) -> unused
    const float* Wg   = (const float*)d_in[10];
    const float* bg   = (const float*)d_in[11];
    const float* Wo   = (const float*)d_in[12];
    const float* bo   = (const float*)d_in[13];
    float* out = (float*)d_out;

    float* wsf = (float*)d_ws;
    float* A      = wsf;                 // 131072
    float* v1     = wsf + 131072;        // theta / s
    float* v2     = wsf + 262144;        // thetap / r
    float* v3     = wsf + 393216;        // thetal
    float* u      = wsf + 524288;        // u
    float* pA     = wsf + 655360;        // 1048576
    float* pB     = pA  + 1048576;       // 1048576
    float* up     = pB  + 1048576;       // 8388608
    float* wm     = up  + 8388608;       // 4096
    float* wz     = wm  + 4096;          // 4096
    // total ~ 11.3M floats = ~45.2 MB

    const float scale = 0.022097086912079608f;   // 1/sqrt(2048)
    dim3 blk(256);
    const int has_loss = (out_size > Bdim * Hdim) ? 1 : 0;

    // A = clip @ Wc^T + bc
    gemv_main<0><<<512, blk, 0, stream>>>(clip, Wc, pA);
    combine<0, 1><<<128, blk, 0, stream>>>(pA, bc, A);

    for (int l = 0; l < 3; ++l) {
        // theta = A @ Wt^T + bt
        gemv_main<0><<<512, blk, 0, stream>>>(A, Wt, pA);
        combine<0, 1><<<128, blk, 0, stream>>>(pA, bt, v1);
        // thetap = theta @ Wp
        gemv_main<1><<<512, blk, 0, stream>>>(v1, Wp, pB);
        combine<0, 0><<<128, blk, 0, stream>>>(pB, nullptr, v2);
        // thetal = thetap @ Wl
        gemv_main<1><<<512, blk, 0, stream>>>(v2, Wl, pA);
        combine<0, 0><<<128, blk, 0, stream>>>(pA, nullptr, v3);
        // fused scores/softmax/weighted-sum over lfb
        flash_chunk<<<4096, blk, 0, stream>>>(lfb, v3, scale, up, wm, wz);
        flash_combine<<<64, blk, 0, stream>>>(up, wm, wz, u);
        // s = u @ Wl^T + bl
        gemv_main<0><<<512, blk, 0, stream>>>(u, Wl, pB);
        combine<0, 1><<<128, blk, 0, stream>>>(pB, bl, v1);
        // t = s @ Wg^T (+bg in LN kernel); r = relu(LN(t))
        gemv_main<0><<<512, blk, 0, stream>>>(v1, Wg, pA);
        ln_relu_from_part<<<64, blk, 0, stream>>>(pA, bg, v2);
        // A += r @ Wo^T + bo
        gemv_main<0><<<512, blk, 0, stream>>>(v2, Wo, pB);
        combine<1, 1><<<128, blk, 0, stream>>>(pB, bo, A);
    }
    finalize_k<<<128, blk, 0, stream>>>(A, out, has_loss);
}